// Round 13
// baseline (476.239 us; speedup 1.0000x reference)
//
#include <hip/hip_runtime.h>

#define N_NODES 100000
#define N_EDGES 3200000
#define NBKT 391     // ceil(100000/256): buckets of 256 dst nodes
#define EPB 8192     // edges per block in bucket passes
#define NBLK_E 391   // ceil(N_EDGES/EPB)
#define NT 25000     // encoder node tiles (4 nodes each)

// bf16 helpers (round-to-nearest-even pack, cheap unpack)
__device__ __forceinline__ unsigned short f2bf(float f) {
    unsigned int u = __float_as_uint(f);
    u += 0x7fff + ((u >> 16) & 1);
    return (unsigned short)(u >> 16);
}
__device__ __forceinline__ float bf2f(unsigned short h) {
    return __uint_as_float(((unsigned int)h) << 16);
}

// ---------- pass A: per-bucket edge counts (LDS-aggregated) ----------
__global__ __launch_bounds__(256) void bucket_hist(const int* __restrict__ dst,
                                                   int* __restrict__ bktcnt) {
    __shared__ int h[NBKT];
    for (int i = threadIdx.x; i < NBKT; i += 256) h[i] = 0;
    __syncthreads();
    const int base = blockIdx.x * EPB;
    #pragma unroll
    for (int k = 0; k < 32; ++k) {
        const int e = base + k * 256 + threadIdx.x;
        if (e < N_EDGES) atomicAdd(&h[dst[e] >> 8], 1);
    }
    __syncthreads();
    for (int i = threadIdx.x; i < NBKT; i += 256)
        if (h[i]) atomicAdd(&bktcnt[i], h[i]);
}

// ---------- scan of bucket counts -> bases + cursors (1 block) ----------
__global__ void bucket_scan(const int* __restrict__ bktcnt, int* __restrict__ bktbase,
                            int* __restrict__ bktcur) {
    __shared__ int s[512];
    const int t = threadIdx.x;
    const int v = (t < NBKT) ? bktcnt[t] : 0;
    s[t] = v;
    __syncthreads();
    #pragma unroll
    for (int off = 1; off < 512; off <<= 1) {
        const int u = (t >= off) ? s[t - off] : 0;
        __syncthreads();
        s[t] += u;
        __syncthreads();
    }
    if (t <= NBKT) {
        const int b = s[t] - v;
        bktbase[t] = b;
        if (t < NBKT) bktcur[t] = b;
    }
}

// ---------- pass B: chunked scatter of packed (src<<8 | dstlocal) ----------
__global__ __launch_bounds__(256) void bucket_scatter(const int* __restrict__ src,
                                                      const int* __restrict__ dst,
                                                      int* __restrict__ bktcur,
                                                      int* __restrict__ pairs) {
    __shared__ int h[NBKT], gb[NBKT], lc[NBKT];
    for (int i = threadIdx.x; i < NBKT; i += 256) h[i] = 0;
    __syncthreads();
    const int base = blockIdx.x * EPB;
    int v[32], bk[32];
    #pragma unroll
    for (int k = 0; k < 32; ++k) {
        const int e = base + k * 256 + threadIdx.x;
        if (e < N_EDGES) {
            const int d = dst[e];
            bk[k] = d >> 8;
            v[k] = (src[e] << 8) | (d & 255);
            atomicAdd(&h[bk[k]], 1);
        } else {
            bk[k] = -1;
        }
    }
    __syncthreads();
    for (int i = threadIdx.x; i < NBKT; i += 256) {
        gb[i] = h[i] ? atomicAdd(&bktcur[i], h[i]) : 0;
        lc[i] = 0;
    }
    __syncthreads();
    #pragma unroll
    for (int k = 0; k < 32; ++k) {
        if (bk[k] >= 0) {
            const int pos = gb[bk[k]] + atomicAdd(&lc[bk[k]], 1);
            pairs[pos] = v[k];
        }
    }
}

// ---------- pass C1: per-bucket degrees -> dinv AND row (in-block scan) ----------
__global__ __launch_bounds__(256) void bucket_deg(const int* __restrict__ pairs,
                                                  const int* __restrict__ bktbase,
                                                  float* __restrict__ dinv,
                                                  int* __restrict__ row) {
    __shared__ int h[256];
    __shared__ int sc[256];
    h[threadIdx.x] = 0;
    __syncthreads();
    const int b = blockIdx.x;
    const int s0 = bktbase[b], s1 = bktbase[b + 1];
    for (int i = s0 + threadIdx.x; i < s1; i += 256) atomicAdd(&h[pairs[i] & 255], 1);
    __syncthreads();
    const int c = h[threadIdx.x];
    sc[threadIdx.x] = c;
    __syncthreads();
    #pragma unroll
    for (int off = 1; off < 256; off <<= 1) {
        const int t = (threadIdx.x >= off) ? sc[threadIdx.x - off] : 0;
        __syncthreads();
        sc[threadIdx.x] += t;
        __syncthreads();
    }
    const int node = (b << 8) + threadIdx.x;
    if (node < N_NODES) {
        dinv[node] = rsqrtf((float)c + 1.0f);
        row[node] = s0 + sc[threadIdx.x] - c;   // exclusive prefix
    }
    if (node == N_NODES) row[N_NODES] = N_EDGES;  // sentinel (b=390, tid=160)
}

// ---------- pass C2: per-bucket CSR fill ----------
__global__ __launch_bounds__(256) void csr_fill(const int* __restrict__ pairs,
                                                const int* __restrict__ bktbase,
                                                const int* __restrict__ row,
                                                int* __restrict__ sorted_src) {
    __shared__ int lc[256];
    lc[threadIdx.x] = 0;
    __syncthreads();
    const int b = blockIdx.x;
    const int s0 = bktbase[b], s1 = bktbase[b + 1];
    const int nbase = b << 8;
    for (int i = s0 + threadIdx.x; i < s1; i += 256) {
        const int p = pairs[i];
        const int dl = p & 255;
        const int pos = row[nbase + dl] + atomicAdd(&lc[dl], 1);
        sorted_src[pos] = p >> 8;
    }
}

// ---------- encoder + GEMM1 (reg-weights; h1 written col-split lo/hi) ----------
__global__ __launch_bounds__(256) void encoder_gemm1(
        const float* __restrict__ x, const float* __restrict__ cnn,
        const float* __restrict__ fcW, const float* __restrict__ fcb,
        const float* __restrict__ cnnW, const float* __restrict__ cnnb,
        const float* __restrict__ W1, unsigned short* __restrict__ h1lo,
        unsigned short* __restrict__ h1hi) {
    __shared__ float s_fcW[32 * 32];
    __shared__ float s_cnnW[128 * 32];
    __shared__ float s_W1[64 * 32];
    __shared__ float s_fcb[32], s_cnnb[32];
    __shared__ float s_in[4][160];   // [wave][0:32)=x row, [32:160)=cnn row
    __shared__ float s_h0[4][64];

    const int tid = threadIdx.x;
    for (int i = tid; i < 32 * 32; i += 256) s_fcW[i] = fcW[i];
    for (int i = tid; i < 128 * 32; i += 256) s_cnnW[i] = cnnW[i];
    for (int i = tid; i < 64 * 32; i += 256) s_W1[i] = W1[i];
    if (tid < 32) { s_fcb[tid] = fcb[tid]; s_cnnb[tid] = cnnb[tid]; }
    __syncthreads();   // one-time: staging -> all-wave reads below

    const int wid = tid >> 6, lane = tid & 63;
    const int o = lane & 31, h = lane >> 5;

    float wfc[16], wcn[64], w1r[32];
    #pragma unroll
    for (int j = 0; j < 16; ++j) wfc[j] = s_fcW[(16 * h + j) * 32 + o];
    #pragma unroll
    for (int j = 0; j < 64; ++j) wcn[j] = s_cnnW[(64 * h + j) * 32 + o];
    #pragma unroll
    for (int j = 0; j < 32; ++j) w1r[j] = s_W1[(32 * h + j) * 32 + o];
    const float bfc = s_fcb[o], bcn = s_cnnb[o];

    float* sin_ = s_in[wid];
    float* sh0 = s_h0[wid];

    int tile = blockIdx.x;
    int node = tile * 4 + wid;
    float xv = (lane < 32) ? x[node * 32 + lane] : 0.0f;
    float c0 = cnn[node * 128 + lane];
    float c1 = cnn[node * 128 + 64 + lane];

    for (; tile < NT; tile += gridDim.x) {
        node = tile * 4 + wid;
        if (lane < 32) sin_[lane] = xv;
        sin_[32 + lane] = c0;
        sin_[96 + lane] = c1;
        const int ntile = tile + gridDim.x;
        const int nnode = (ntile < NT) ? ntile * 4 + wid : node;
        xv = (lane < 32) ? x[nnode * 32 + lane] : 0.0f;
        c0 = cnn[nnode * 128 + lane];
        c1 = cnn[nnode * 128 + 64 + lane];
        float afc = 0.0f, acn = 0.0f;
        #pragma unroll
        for (int j = 0; j < 16; j += 4) {
            const float4 iv = *reinterpret_cast<const float4*>(&sin_[16 * h + j]);
            afc = fmaf(iv.x, wfc[j], afc);
            afc = fmaf(iv.y, wfc[j + 1], afc);
            afc = fmaf(iv.z, wfc[j + 2], afc);
            afc = fmaf(iv.w, wfc[j + 3], afc);
        }
        #pragma unroll
        for (int j = 0; j < 64; j += 4) {
            const float4 iv = *reinterpret_cast<const float4*>(&sin_[32 + 64 * h + j]);
            acn = fmaf(iv.x, wcn[j], acn);
            acn = fmaf(iv.y, wcn[j + 1], acn);
            acn = fmaf(iv.z, wcn[j + 2], acn);
            acn = fmaf(iv.w, wcn[j + 3], acn);
        }
        afc += __shfl_xor(afc, 32);
        acn += __shfl_xor(acn, 32);
        const float h0v = (lane < 32) ? fmaxf(afc + bfc, 0.0f)
                                      : fmaxf(acn + bcn, 0.0f);
        sh0[lane] = h0v;
        float a1 = 0.0f;
        #pragma unroll
        for (int j = 0; j < 32; j += 4) {
            const float4 iv = *reinterpret_cast<const float4*>(&sh0[32 * h + j]);
            a1 = fmaf(iv.x, w1r[j], a1);
            a1 = fmaf(iv.y, w1r[j + 1], a1);
            a1 = fmaf(iv.z, w1r[j + 2], a1);
            a1 = fmaf(iv.w, w1r[j + 3], a1);
        }
        a1 += __shfl_xor(a1, 32);
        if (lane < 16) h1lo[node * 16 + lane] = f2bf(a1);
        else if (lane < 32) h1hi[node * 16 + (lane - 16)] = f2bf(a1);
    }
}

// ---------- conv1a: gather h1lo (3.2MB, L2-resident) -> raw agg_lo (f32) ----------
// wave = 1 node; 16 cols x 4 edge-streams. 4-deep unroll.
__global__ __launch_bounds__(256) void conv1a(
        const unsigned short* __restrict__ h1lo, const int* __restrict__ row,
        const int* __restrict__ ss, const float* __restrict__ dinv,
        const float* __restrict__ b1, float* __restrict__ agg_lo) {
    __shared__ float sb1[16];
    const int tid = threadIdx.x;
    if (tid < 16) sb1[tid] = b1[tid];
    __syncthreads();   // stage-before-use (R3 lesson)

    const int wid = tid >> 6, lane = tid & 63;
    const int c = lane & 15, q = lane >> 4;
    const int node = blockIdx.x * 4 + wid;

    const float di = dinv[node];
    float acc = (q == 0) ? bf2f(h1lo[node * 16 + c]) * di * di + sb1[c] : 0.0f;
    const int end = row[node + 1];
    int i = row[node] + q;
    for (; i + 12 < end; i += 16) {
        const int s0 = ss[i], s1 = ss[i + 4], s2 = ss[i + 8], s3 = ss[i + 12];
        const float w0 = dinv[s0] * di, w1 = dinv[s1] * di;
        const float w2 = dinv[s2] * di, w3 = dinv[s3] * di;
        const float v0 = bf2f(h1lo[s0 * 16 + c]), v1 = bf2f(h1lo[s1 * 16 + c]);
        const float v2 = bf2f(h1lo[s2 * 16 + c]), v3 = bf2f(h1lo[s3 * 16 + c]);
        acc = fmaf(v0, w0, acc);
        acc = fmaf(v1, w1, acc);
        acc = fmaf(v2, w2, acc);
        acc = fmaf(v3, w3, acc);
    }
    for (; i < end; i += 4) {
        const int s = ss[i];
        acc = fmaf(bf2f(h1lo[s * 16 + c]), dinv[s] * di, acc);
    }
    acc += __shfl_xor(acc, 16);
    acc += __shfl_xor(acc, 32);
    if (q == 0) agg_lo[node * 16 + c] = acc;   // pre-ReLU
}

// ---------- conv1b: gather h1hi + readback agg_lo -> ReLU + GEMM2 -> h2a,h2c ----------
__global__ __launch_bounds__(256) void conv1b(
        const unsigned short* __restrict__ h1hi, const int* __restrict__ row,
        const int* __restrict__ ss, const float* __restrict__ dinv,
        const float* __restrict__ b1, const float* __restrict__ W2,
        const float* __restrict__ agg_lo, unsigned short* __restrict__ h2a,
        unsigned short* __restrict__ h2c) {
    __shared__ float sW2[32 * 20];
    __shared__ float sb1h[16];
    __shared__ float sa[4][33];
    const int tid = threadIdx.x;
    for (int i = tid; i < 32 * 20; i += 256) sW2[i] = W2[i];
    if (tid < 16) sb1h[tid] = b1[16 + tid];
    __syncthreads();   // stage-before-use (R3 lesson)

    const int wid = tid >> 6, lane = tid & 63;
    const int c = lane & 15, q = lane >> 4;
    const int node = blockIdx.x * 4 + wid;

    // issue agg_lo readback early (hidden under the edge loop)
    const float al = (q == 1) ? agg_lo[node * 16 + c] : 0.0f;

    const float di = dinv[node];
    float acc = (q == 0) ? bf2f(h1hi[node * 16 + c]) * di * di + sb1h[c] : 0.0f;
    const int end = row[node + 1];
    int i = row[node] + q;
    for (; i + 12 < end; i += 16) {
        const int s0 = ss[i], s1 = ss[i + 4], s2 = ss[i + 8], s3 = ss[i + 12];
        const float w0 = dinv[s0] * di, w1 = dinv[s1] * di;
        const float w2 = dinv[s2] * di, w3 = dinv[s3] * di;
        const float v0 = bf2f(h1hi[s0 * 16 + c]), v1 = bf2f(h1hi[s1 * 16 + c]);
        const float v2 = bf2f(h1hi[s2 * 16 + c]), v3 = bf2f(h1hi[s3 * 16 + c]);
        acc = fmaf(v0, w0, acc);
        acc = fmaf(v1, w1, acc);
        acc = fmaf(v2, w2, acc);
        acc = fmaf(v3, w3, acc);
    }
    for (; i < end; i += 4) {
        const int s = ss[i];
        acc = fmaf(bf2f(h1hi[s * 16 + c]), dinv[s] * di, acc);
    }
    acc += __shfl_xor(acc, 16);
    acc += __shfl_xor(acc, 32);
    // assemble full relu(agg) row in wave-private LDS (in-order DS per wave)
    if (q == 0) sa[wid][16 + c] = fmaxf(acc, 0.0f);
    if (q == 1) sa[wid][c] = fmaxf(al, 0.0f);

    if (lane < 20) {
        float o = 0.0f;
        #pragma unroll
        for (int k = 0; k < 32; ++k) o = fmaf(sa[wid][k], sW2[k * 20 + lane], o);
        if (lane < 16) h2a[node * 16 + lane] = f2bf(o);
        else h2c[node * 4 + (lane - 16)] = f2bf(o);
    }
}

// ---------- conv2a: gather h2a (cols 0-15) -> out[:,0:16) ----------
__global__ __launch_bounds__(256) void conv2a(
        const unsigned short* __restrict__ h2a, const int* __restrict__ row,
        const int* __restrict__ ss, const float* __restrict__ dinv,
        const float* __restrict__ b2, float* __restrict__ out) {
    __shared__ float sb2[16];
    const int tid = threadIdx.x;
    if (tid < 16) sb2[tid] = b2[tid];
    __syncthreads();

    const int wid = tid >> 6, lane = tid & 63;
    const int c = lane & 15, q = lane >> 4;
    const int node = blockIdx.x * 4 + wid;

    const float di = dinv[node];
    float acc = (q == 0) ? bf2f(h2a[node * 16 + c]) * di * di + sb2[c] : 0.0f;
    const int end = row[node + 1];
    int i = row[node] + q;
    for (; i + 12 < end; i += 16) {
        const int s0 = ss[i], s1 = ss[i + 4], s2 = ss[i + 8], s3 = ss[i + 12];
        const float w0 = dinv[s0] * di, w1 = dinv[s1] * di;
        const float w2 = dinv[s2] * di, w3 = dinv[s3] * di;
        const float v0 = bf2f(h2a[s0 * 16 + c]), v1 = bf2f(h2a[s1 * 16 + c]);
        const float v2 = bf2f(h2a[s2 * 16 + c]), v3 = bf2f(h2a[s3 * 16 + c]);
        acc = fmaf(v0, w0, acc);
        acc = fmaf(v1, w1, acc);
        acc = fmaf(v2, w2, acc);
        acc = fmaf(v3, w3, acc);
    }
    for (; i < end; i += 4) {
        const int s = ss[i];
        acc = fmaf(bf2f(h2a[s * 16 + c]), dinv[s] * di, acc);
    }
    acc += __shfl_xor(acc, 16);
    acc += __shfl_xor(acc, 32);
    if (q == 0) out[node * 20 + c] = acc;
}

// ---------- conv2b: gather h2c (cols 16-19, 0.8MB fully L2-resident) ----------
// 4 cols x 16 edge-streams; 2-deep unroll.
__global__ __launch_bounds__(256) void conv2b(
        const unsigned short* __restrict__ h2c, const int* __restrict__ row,
        const int* __restrict__ ss, const float* __restrict__ dinv,
        const float* __restrict__ b2, float* __restrict__ out) {
    __shared__ float sb2h[4];
    const int tid = threadIdx.x;
    if (tid < 4) sb2h[tid] = b2[16 + tid];
    __syncthreads();

    const int wid = tid >> 6, lane = tid & 63;
    const int c = lane & 3, q = lane >> 2;   // 16 streams
    const int node = blockIdx.x * 4 + wid;

    const float di = dinv[node];
    float acc = (q == 0) ? bf2f(h2c[node * 4 + c]) * di * di + sb2h[c] : 0.0f;
    const int end = row[node + 1];
    int i = row[node] + q;
    for (; i + 16 < end; i += 32) {
        const int s0 = ss[i], s1 = ss[i + 16];
        const float w0 = dinv[s0] * di, w1 = dinv[s1] * di;
        const float v0 = bf2f(h2c[s0 * 4 + c]), v1 = bf2f(h2c[s1 * 4 + c]);
        acc = fmaf(v0, w0, acc);
        acc = fmaf(v1, w1, acc);
    }
    for (; i < end; i += 16) {
        const int s = ss[i];
        acc = fmaf(bf2f(h2c[s * 4 + c]), dinv[s] * di, acc);
    }
    acc += __shfl_xor(acc, 4);
    acc += __shfl_xor(acc, 8);
    acc += __shfl_xor(acc, 16);
    acc += __shfl_xor(acc, 32);
    if (q == 0) out[node * 20 + 16 + c] = acc;
}

extern "C" void kernel_launch(void* const* d_in, const int* in_sizes, int n_in,
                              void* d_out, int out_size, void* d_ws, size_t ws_size,
                              hipStream_t stream) {
    const float* x    = (const float*)d_in[0];
    const float* cnn  = (const float*)d_in[1];
    const int*   ei   = (const int*)d_in[2];
    const float* fcW  = (const float*)d_in[3];
    const float* fcb  = (const float*)d_in[4];
    const float* cnnW = (const float*)d_in[5];
    const float* cnnb = (const float*)d_in[6];
    const float* W1   = (const float*)d_in[7];
    const float* b1   = (const float*)d_in[8];
    const float* W2   = (const float*)d_in[9];
    const float* b2   = (const float*)d_in[10];

    const int* srcp = ei;
    const int* dstp = ei + N_EDGES;

    // workspace layout (4-byte units), total ~44 MB
    float* ws      = (float*)d_ws;
    float* dinv    = ws;                        // [100352]
    int*   row     = (int*)(ws + 100352);       // [100608] (N+1 used)
    int*   bktcnt  = (int*)(ws + 200960);       // [512]
    int*   bktbase = (int*)(ws + 201472);       // [512] (NBKT+1 used)
    int*   bktcur  = (int*)(ws + 201984);       // [512]
    int*   pairs   = (int*)(ws + 202496);       // [N_EDGES]
    int*   sorted  = (int*)(ws + 202496 + N_EDGES);  // [N_EDGES]
    float* base2   = ws + 202496 + 2 * N_EDGES;
    unsigned short* h1lo = (unsigned short*)base2;               // [N*16] bf16
    unsigned short* h1hi = (unsigned short*)(base2 + 800000);    // [N*16] bf16
    float* agg_lo  = base2 + 1600000;                            // [N*16] f32
    unsigned short* h2a = (unsigned short*)(base2 + 3200000);    // [N*16] bf16
    unsigned short* h2c = (unsigned short*)(base2 + 4000000);    // [N*4]  bf16
    float* out     = (float*)d_out;

    // --- bucketed CSR build ---
    hipMemsetAsync(bktcnt, 0, 512 * sizeof(int), stream);
    bucket_hist<<<NBLK_E, 256, 0, stream>>>(dstp, bktcnt);
    bucket_scan<<<1, 512, 0, stream>>>(bktcnt, bktbase, bktcur);
    bucket_scatter<<<NBLK_E, 256, 0, stream>>>(srcp, dstp, bktcur, pairs);
    bucket_deg<<<NBKT, 256, 0, stream>>>(pairs, bktbase, dinv, row);
    csr_fill<<<NBKT, 256, 0, stream>>>(pairs, bktbase, row, sorted);

    // --- encoder + first linear (persistent, barrier-free loop) ---
    encoder_gemm1<<<1280, 256, 0, stream>>>(x, cnn, fcW, fcb, cnnW, cnnb, W1,
                                            h1lo, h1hi);

    // --- conv1 in two L2-sized passes ---
    conv1a<<<N_NODES / 4, 256, 0, stream>>>(h1lo, row, sorted, dinv, b1, agg_lo);
    conv1b<<<N_NODES / 4, 256, 0, stream>>>(h1hi, row, sorted, dinv, b1, W2,
                                            agg_lo, h2a, h2c);

    // --- conv2 in two L2-sized passes ---
    conv2a<<<N_NODES / 4, 256, 0, stream>>>(h2a, row, sorted, dinv, b2, out);
    conv2b<<<N_NODES / 4, 256, 0, stream>>>(h2c, row, sorted, dinv, b2, out);
}